// Round 2
// baseline (917.157 us; speedup 1.0000x reference)
//
#include <hip/hip_runtime.h>
#include <hip/hip_bf16.h>
#include <stdint.h>

// Problem constants (from reference)
#define BS   4
#define LSEQ 2048
#define HID  1024
#define NH   16
#define HD   64
#define RREG 4
#define M_TOT (BS * LSEQ)   // 8192
#define NKV   (NH * HD)     // 1024

// GEMM tiling
#define BM 128
#define BN 128
#define BK 16

__device__ __forceinline__ float relu_f(float x) { return x > 0.0f ? x : 0.0f; }

// MODE 0: V path  -> V1[m][n] = relu(A@Wv + bv)
// MODE 1: K path  -> dot[m][h] = sum_d relu(A@Wk + bk)[m, h*64+d] * RH[h][d];  valid = dot > 0.5
template <int MODE>
__global__ __launch_bounds__(256) void fused_gemm(
    const float* __restrict__ A,      // [M_TOT, HID]
    const float* __restrict__ W,      // [HID, NKV]
    const float* __restrict__ bias,   // [NKV]
    const float* __restrict__ RH,     // [NH, HD]   (MODE 1)
    float* __restrict__ V1,           // [M_TOT, NKV] (MODE 0)
    unsigned char* __restrict__ validB) // [BS*NH*LSEQ], layout [b][h][l] (MODE 1)
{
    __shared__ float As[BK][BM + 8];  // transposed A tile: As[k][m], row stride 136 floats
    __shared__ float Bs[BK][BN];

    const int tid = threadIdx.x;
    const int tx  = tid & 15;   // col group
    const int ty  = tid >> 4;   // row group
    const int bm  = blockIdx.x;
    const int bn  = blockIdx.y;

    float acc[8][8];
#pragma unroll
    for (int i = 0; i < 8; ++i)
#pragma unroll
        for (int j = 0; j < 8; ++j) acc[i][j] = 0.0f;

    for (int k0 = 0; k0 < HID; k0 += BK) {
        // Stage A tile (128 rows x 16 k), transposed into LDS
#pragma unroll
        for (int it = 0; it < 2; ++it) {
            int f  = tid + 256 * it;       // 0..511
            int ar = f >> 2;               // 0..127
            int ac = (f & 3) << 2;         // 0,4,8,12
            const float4 v = *(const float4*)&A[(size_t)(bm * BM + ar) * HID + k0 + ac];
            As[ac + 0][ar] = v.x;
            As[ac + 1][ar] = v.y;
            As[ac + 2][ar] = v.z;
            As[ac + 3][ar] = v.w;
        }
        // Stage B tile (16 k x 128 cols)
#pragma unroll
        for (int it = 0; it < 2; ++it) {
            int f  = tid + 256 * it;       // 0..511
            int br = f >> 5;               // 0..15
            int bc = (f & 31) << 2;        // 0..124
            *(float4*)&Bs[br][bc] = *(const float4*)&W[(size_t)(k0 + br) * NKV + bn * BN + bc];
        }
        __syncthreads();

#pragma unroll
        for (int kk = 0; kk < BK; ++kk) {
            float a[8], b[8];
            *(float4*)&a[0] = *(const float4*)&As[kk][ty * 4];
            *(float4*)&a[4] = *(const float4*)&As[kk][64 + ty * 4];
            *(float4*)&b[0] = *(const float4*)&Bs[kk][tx * 4];
            *(float4*)&b[4] = *(const float4*)&Bs[kk][64 + tx * 4];
#pragma unroll
            for (int i = 0; i < 8; ++i)
#pragma unroll
                for (int j = 0; j < 8; ++j)
                    acc[i][j] = fmaf(a[i], b[j], acc[i][j]);
        }
        __syncthreads();
    }

    if constexpr (MODE == 0) {
        // Epilogue: relu + bias, store V1
#pragma unroll
        for (int i = 0; i < 8; ++i) {
            int lr  = (i < 4) ? (ty * 4 + i) : (64 + ty * 4 + (i - 4));
            size_t row = (size_t)(bm * BM + lr);
            float4 o0, o1;
            o0.x = relu_f(acc[i][0] + bias[bn * BN + tx * 4 + 0]);
            o0.y = relu_f(acc[i][1] + bias[bn * BN + tx * 4 + 1]);
            o0.z = relu_f(acc[i][2] + bias[bn * BN + tx * 4 + 2]);
            o0.w = relu_f(acc[i][3] + bias[bn * BN + tx * 4 + 3]);
            o1.x = relu_f(acc[i][4] + bias[bn * BN + 64 + tx * 4 + 0]);
            o1.y = relu_f(acc[i][5] + bias[bn * BN + 64 + tx * 4 + 1]);
            o1.z = relu_f(acc[i][6] + bias[bn * BN + 64 + tx * 4 + 2]);
            o1.w = relu_f(acc[i][7] + bias[bn * BN + 64 + tx * 4 + 3]);
            *(float4*)&V1[row * NKV + bn * BN + tx * 4]      = o0;
            *(float4*)&V1[row * NKV + bn * BN + 64 + tx * 4] = o1;
        }
    } else {
        // Epilogue: per-row, per-head dot with ReadingHead, then threshold.
        // 128-col tile == heads h0 = bn*2 (cols 0..63) and h0+1 (cols 64..127).
        __shared__ float red[256][17];
        const int h0 = bn * 2;
#pragma unroll
        for (int i = 0; i < 8; ++i) {
            int lr = (i < 4) ? (ty * 4 + i) : (64 + ty * 4 + (i - 4));
            float s0 = 0.0f, s1 = 0.0f;
#pragma unroll
            for (int j = 0; j < 4; ++j) {
                int c = tx * 4 + j;  // d-index within head (0..63)
                float v0 = relu_f(acc[i][j]     + bias[bn * BN + c]);
                float v1 = relu_f(acc[i][4 + j] + bias[bn * BN + 64 + c]);
                s0 += v0 * RH[h0 * HD + c];
                s1 += v1 * RH[(h0 + 1) * HD + c];
            }
            red[lr][tx]       = s0;   // head h0 partials, rows 0..127
            red[128 + lr][tx] = s1;   // head h0+1 partials
        }
        __syncthreads();
        // 256 threads: t = j*128 + lr ; sum 16 partials
        int j  = tid >> 7;        // 0/1
        int lr = tid & 127;
        float s = 0.0f;
#pragma unroll
        for (int x = 0; x < 16; ++x) s += red[tid][x];
        int h    = h0 + j;
        int grow = bm * BM + lr;
        int b    = grow >> 11;    // /2048
        int l    = grow & 2047;
        validB[((size_t)b * NH + h) * LSEQ + l] = (s > 0.5f) ? 1 : 0;
        (void)j; (void)lr;
    }
}

// 4-slot shift-register scans; one thread per (b,h,direction).
// idxb layout: [M_TOT][NH][8] int16 -- slots 0..3 fwd, 4..7 bwd.
__global__ void scan_kernel(const unsigned char* __restrict__ validB,
                            short* __restrict__ idxb)
{
    int t = threadIdx.x;          // 0..127
    int p = t & 63;
    int b = p >> 4;
    int h = p & 15;
    const unsigned char* v = validB + ((size_t)b * NH + h) * LSEQ;

    if (t < 64) {
        // forward: F[0]=0s; F[l] = valid[l] ? [l, F[l-1][0..2]] : F[l-1]
        int f0 = 0, f1 = 0, f2 = 0, f3 = 0;
        *(uint64_t*)(idxb + (((size_t)(b * LSEQ + 0) * NH + h) * 8 + 0)) = 0ull;
        for (int l = 1; l < LSEQ; ++l) {
            if (v[l]) { f3 = f2; f2 = f1; f1 = f0; f0 = l; }
            uint64_t pk = (uint64_t)(uint16_t)f0 | ((uint64_t)(uint16_t)f1 << 16) |
                          ((uint64_t)(uint16_t)f2 << 32) | ((uint64_t)(uint16_t)f3 << 48);
            *(uint64_t*)(idxb + (((size_t)(b * LSEQ + l) * NH + h) * 8 + 0)) = pk;
        }
    } else {
        // backward: B[L-1] = [valid[L-1]?L-1:0, 0,0,0];
        // B[l] = valid[l] ? [l+1, B[l+1][0..2]] : B[l+1]  (l = L-2..1); B[0]=0s
        int g0 = v[LSEQ - 1] ? (LSEQ - 1) : 0;
        int g1 = 0, g2 = 0, g3 = 0;
        {
            uint64_t pk = (uint64_t)(uint16_t)g0;
            *(uint64_t*)(idxb + (((size_t)(b * LSEQ + (LSEQ - 1)) * NH + h) * 8 + 4)) = pk;
        }
        for (int l = LSEQ - 2; l >= 1; --l) {
            if (v[l]) { g3 = g2; g2 = g1; g1 = g0; g0 = l + 1; }
            uint64_t pk = (uint64_t)(uint16_t)g0 | ((uint64_t)(uint16_t)g1 << 16) |
                          ((uint64_t)(uint16_t)g2 << 32) | ((uint64_t)(uint16_t)g3 << 48);
            *(uint64_t*)(idxb + (((size_t)(b * LSEQ + l) * NH + h) * 8 + 4)) = pk;
        }
        *(uint64_t*)(idxb + (((size_t)(b * LSEQ + 0) * NH + h) * 8 + 4)) = 0ull;
    }
}

// One wave per (gr, h): lane d computes out[gr][h*64+d] = sum_r wf[r]*V1[b,fr,h,d] + wb[r]*V1[b,br,h,d]
__global__ __launch_bounds__(256) void gather_kernel(
    const float* __restrict__ V1,     // [M_TOT, NKV]
    const short* __restrict__ idxb,   // [M_TOT][NH][8]
    const float* __restrict__ bw,     // [NH, 2*RREG]
    float* __restrict__ out)          // [M_TOT, NKV]
{
    int wid  = (blockIdx.x * 256 + threadIdx.x) >> 6;
    int lane = threadIdx.x & 63;
    int gr   = wid >> 4;   // 0..M_TOT-1
    int h    = wid & 15;
    int b    = gr >> 11;   // /2048

    const ushort4* ip = (const ushort4*)(idxb + ((size_t)gr * NH + h) * 8);
    ushort4 i0 = ip[0];
    ushort4 i1 = ip[1];

    const float* wp    = bw + h * 8;
    const float* vbase = V1 + (size_t)b * LSEQ * NKV + h * HD + lane;

    float acc = wp[0] * vbase[(size_t)i0.x * NKV] + wp[1] * vbase[(size_t)i0.y * NKV] +
                wp[2] * vbase[(size_t)i0.z * NKV] + wp[3] * vbase[(size_t)i0.w * NKV] +
                wp[4] * vbase[(size_t)i1.x * NKV] + wp[5] * vbase[(size_t)i1.y * NKV] +
                wp[6] * vbase[(size_t)i1.z * NKV] + wp[7] * vbase[(size_t)i1.w * NKV];

    out[(size_t)gr * NKV + h * HD + lane] = acc;
}

extern "C" void kernel_launch(void* const* d_in, const int* in_sizes, int n_in,
                              void* d_out, int out_size, void* d_ws, size_t ws_size,
                              hipStream_t stream)
{
    const float* hs = (const float*)d_in[0];  // [4,2048,1024]
    const float* Wk = (const float*)d_in[1];  // [1024,1024]
    const float* bk = (const float*)d_in[2];  // [1024]
    const float* Wv = (const float*)d_in[3];  // [1024,1024]
    const float* bv = (const float*)d_in[4];  // [1024]
    const float* RH = (const float*)d_in[5];  // [16,64]
    const float* bw = (const float*)d_in[6];  // [16,8]
    float* out = (float*)d_out;

    char* ws = (char*)d_ws;
    float* V1             = (float*)ws;                                  // 32 MiB
    unsigned char* validB = (unsigned char*)(ws + (size_t)M_TOT * NKV * 4);        // 128 KiB
    short* idxb           = (short*)(ws + (size_t)M_TOT * NKV * 4 + (size_t)M_TOT * NH); // 2 MiB, 8B-aligned

    dim3 g1(M_TOT / BM, NKV / BN);  // (64, 8)
    fused_gemm<0><<<g1, 256, 0, stream>>>(hs, Wv, bv, nullptr, V1, nullptr);
    fused_gemm<1><<<g1, 256, 0, stream>>>(hs, Wk, bk, RH, nullptr, validB);
    scan_kernel<<<1, 128, 0, stream>>>(validB, idxb);
    gather_kernel<<<(M_TOT * NH) / 4, 256, 0, stream>>>(V1, idxb, bw, out);
}

// Round 3
// 549.928 us; speedup vs baseline: 1.6678x; 1.6678x over previous
//
#include <hip/hip_runtime.h>
#include <hip/hip_bf16.h>
#include <stdint.h>

// Problem constants (from reference)
#define BS   4
#define LSEQ 2048
#define HID  1024
#define NH   16
#define HD   64
#define RREG 4
#define M_TOT (BS * LSEQ)   // 8192
#define NKV   (NH * HD)     // 1024

// GEMM tiling
#define BM 128
#define BN 128
#define BK 16

__device__ __forceinline__ float relu_f(float x) { return x > 0.0f ? x : 0.0f; }

// MODE 0: V path  -> V1[m][n] = relu(A@Wv + bv)
// MODE 1: K path  -> dot[m][h] = sum_d relu(A@Wk + bk)[m, h*64+d] * RH[h][d];  valid = dot > 0.5
template <int MODE>
__global__ __launch_bounds__(256) void fused_gemm(
    const float* __restrict__ A,      // [M_TOT, HID]
    const float* __restrict__ W,      // [HID, NKV]
    const float* __restrict__ bias,   // [NKV]
    const float* __restrict__ RH,     // [NH, HD]   (MODE 1)
    float* __restrict__ V1,           // [M_TOT, NKV] (MODE 0)
    unsigned char* __restrict__ validB) // [BS*NH*LSEQ], layout [b][h][l] (MODE 1)
{
    __shared__ float As[BK][BM + 8];  // transposed A tile: As[k][m]
    __shared__ float Bs[BK][BN];

    const int tid = threadIdx.x;
    const int tx  = tid & 15;   // col group
    const int ty  = tid >> 4;   // row group
    const int bm  = blockIdx.x;
    const int bn  = blockIdx.y;

    float acc[8][8];
#pragma unroll
    for (int i = 0; i < 8; ++i)
#pragma unroll
        for (int j = 0; j < 8; ++j) acc[i][j] = 0.0f;

    for (int k0 = 0; k0 < HID; k0 += BK) {
#pragma unroll
        for (int it = 0; it < 2; ++it) {
            int f  = tid + 256 * it;       // 0..511
            int ar = f >> 2;               // 0..127
            int ac = (f & 3) << 2;         // 0,4,8,12
            const float4 v = *(const float4*)&A[(size_t)(bm * BM + ar) * HID + k0 + ac];
            As[ac + 0][ar] = v.x;
            As[ac + 1][ar] = v.y;
            As[ac + 2][ar] = v.z;
            As[ac + 3][ar] = v.w;
        }
#pragma unroll
        for (int it = 0; it < 2; ++it) {
            int f  = tid + 256 * it;       // 0..511
            int br = f >> 5;               // 0..15
            int bc = (f & 31) << 2;        // 0..124
            *(float4*)&Bs[br][bc] = *(const float4*)&W[(size_t)(k0 + br) * NKV + bn * BN + bc];
        }
        __syncthreads();

#pragma unroll
        for (int kk = 0; kk < BK; ++kk) {
            float a[8], b[8];
            *(float4*)&a[0] = *(const float4*)&As[kk][ty * 4];
            *(float4*)&a[4] = *(const float4*)&As[kk][64 + ty * 4];
            *(float4*)&b[0] = *(const float4*)&Bs[kk][tx * 4];
            *(float4*)&b[4] = *(const float4*)&Bs[kk][64 + tx * 4];
#pragma unroll
            for (int i = 0; i < 8; ++i)
#pragma unroll
                for (int j = 0; j < 8; ++j)
                    acc[i][j] = fmaf(a[i], b[j], acc[i][j]);
        }
        __syncthreads();
    }

    if constexpr (MODE == 0) {
#pragma unroll
        for (int i = 0; i < 8; ++i) {
            int lr  = (i < 4) ? (ty * 4 + i) : (64 + ty * 4 + (i - 4));
            size_t row = (size_t)(bm * BM + lr);
            float4 o0, o1;
            o0.x = relu_f(acc[i][0] + bias[bn * BN + tx * 4 + 0]);
            o0.y = relu_f(acc[i][1] + bias[bn * BN + tx * 4 + 1]);
            o0.z = relu_f(acc[i][2] + bias[bn * BN + tx * 4 + 2]);
            o0.w = relu_f(acc[i][3] + bias[bn * BN + tx * 4 + 3]);
            o1.x = relu_f(acc[i][4] + bias[bn * BN + 64 + tx * 4 + 0]);
            o1.y = relu_f(acc[i][5] + bias[bn * BN + 64 + tx * 4 + 1]);
            o1.z = relu_f(acc[i][6] + bias[bn * BN + 64 + tx * 4 + 2]);
            o1.w = relu_f(acc[i][7] + bias[bn * BN + 64 + tx * 4 + 3]);
            *(float4*)&V1[row * NKV + bn * BN + tx * 4]      = o0;
            *(float4*)&V1[row * NKV + bn * BN + 64 + tx * 4] = o1;
        }
    } else {
        // Epilogue: per-row, per-head dot with ReadingHead, then threshold.
        __shared__ float red[256][17];
        const int h0 = bn * 2;
#pragma unroll
        for (int i = 0; i < 8; ++i) {
            int lr = (i < 4) ? (ty * 4 + i) : (64 + ty * 4 + (i - 4));
            float s0 = 0.0f, s1 = 0.0f;
#pragma unroll
            for (int j = 0; j < 4; ++j) {
                int c = tx * 4 + j;  // d-index within head (0..63)
                float v0 = relu_f(acc[i][j]     + bias[bn * BN + c]);
                float v1 = relu_f(acc[i][4 + j] + bias[bn * BN + 64 + c]);
                s0 += v0 * RH[h0 * HD + c];
                s1 += v1 * RH[(h0 + 1) * HD + c];
            }
            red[lr][tx]       = s0;
            red[128 + lr][tx] = s1;
        }
        __syncthreads();
        int j  = tid >> 7;        // 0/1
        int lr = tid & 127;
        float s = 0.0f;
#pragma unroll
        for (int x = 0; x < 16; ++x) s += red[tid][x];
        int h    = h0 + j;
        int grow = bm * BM + lr;
        int b    = grow >> 11;    // /2048
        int l    = grow & 2047;
        validB[((size_t)b * NH + h) * LSEQ + l] = (s > 0.5f) ? 1 : 0;
    }
}

// Parallel nearest-valid-position extraction.
// Forward regs at l:  last 4 valid positions l' in [1..l], descending, value l'.
// Backward regs at l (1<=l<=L-1): first 4 valid positions l' in [l..L-1],
//   ascending, value min(l'+1, L-1).  Position 0: all zeros (both maps).
// One block per (b,h); 2048-bit validity mask in LDS; per-position bit scans.
__global__ __launch_bounds__(256) void scan_kernel(
    const unsigned char* __restrict__ validB,
    short* __restrict__ idxb)   // [M_TOT][NH][8]: slots 0..3 fwd, 4..7 bwd
{
    const int bh = blockIdx.x;      // 0..63
    const int b  = bh >> 4;
    const int h  = bh & 15;
    const unsigned char* v = validB + ((size_t)b * NH + h) * LSEQ;

    __shared__ uint64_t words[LSEQ / 64];   // 32 words

    const int tid  = threadIdx.x;           // 0..255
    const int lane = tid & 63;
    const int wv   = tid >> 6;              // wave 0..3

    // Build the bitmask: each wave ballots 64 consecutive positions.
#pragma unroll
    for (int it = 0; it < LSEQ / 256; ++it) {       // 8 iters
        int p = it * 256 + wv * 64 + lane;
        uint64_t m = __ballot(v[p] != 0);
        if (lane == 0) {
            if ((p >> 6) == 0) m &= ~1ull;          // valid[0] never participates
            words[p >> 6] = m;
        }
    }
    __syncthreads();

#pragma unroll
    for (int it = 0; it < LSEQ / 256; ++it) {
        int l = it * 256 + tid;
        ushort f[4] = {0, 0, 0, 0};
        ushort g[4] = {0, 0, 0, 0};
        if (l > 0) {
            // forward: last 4 set bits <= l
            {
                int wi = l >> 6, bi = l & 63;
                uint64_t m = words[wi] & ((bi == 63) ? ~0ull : ((2ull << bi) - 1));
                int cnt = 0;
                while (cnt < 4) {
                    if (m == 0) {
                        if (wi == 0) break;
                        m = words[--wi];
                        continue;
                    }
                    int p = 63 - __clzll(m);
                    f[cnt++] = (ushort)(wi * 64 + p);
                    m &= ~(1ull << p);
                }
            }
            // backward: first 4 set bits >= l, value min(p+1, L-1)
            {
                int wi = l >> 6, bi = l & 63;
                uint64_t m = words[wi] & (~0ull << bi);
                int cnt = 0;
                while (cnt < 4) {
                    if (m == 0) {
                        if (wi == (LSEQ / 64) - 1) break;
                        m = words[++wi];
                        continue;
                    }
                    int p = __ffsll((long long)m) - 1;
                    int pos = wi * 64 + p;
                    g[cnt++] = (ushort)((pos >= LSEQ - 1) ? (LSEQ - 1) : (pos + 1));
                    m &= m - 1;
                }
            }
        }
        uint4 pk;
        pk.x = (uint32_t)f[0] | ((uint32_t)f[1] << 16);
        pk.y = (uint32_t)f[2] | ((uint32_t)f[3] << 16);
        pk.z = (uint32_t)g[0] | ((uint32_t)g[1] << 16);
        pk.w = (uint32_t)g[2] | ((uint32_t)g[3] << 16);
        *(uint4*)(idxb + (((size_t)(b * LSEQ + l)) * NH + h) * 8) = pk;
    }
}

// One wave per (gr, h): lane d computes out[gr][h*64+d] = sum_r wf[r]*V1[b,fr,h,d] + wb[r]*V1[b,br,h,d]
__global__ __launch_bounds__(256) void gather_kernel(
    const float* __restrict__ V1,     // [M_TOT, NKV]
    const short* __restrict__ idxb,   // [M_TOT][NH][8]
    const float* __restrict__ bw,     // [NH, 2*RREG]
    float* __restrict__ out)          // [M_TOT, NKV]
{
    int wid  = (blockIdx.x * 256 + threadIdx.x) >> 6;
    int lane = threadIdx.x & 63;
    int gr   = wid >> 4;   // 0..M_TOT-1
    int h    = wid & 15;
    int b    = gr >> 11;   // /2048

    const ushort4* ip = (const ushort4*)(idxb + ((size_t)gr * NH + h) * 8);
    ushort4 i0 = ip[0];
    ushort4 i1 = ip[1];

    const float* wp    = bw + h * 8;
    const float* vbase = V1 + (size_t)b * LSEQ * NKV + h * HD + lane;

    float acc = wp[0] * vbase[(size_t)i0.x * NKV] + wp[1] * vbase[(size_t)i0.y * NKV] +
                wp[2] * vbase[(size_t)i0.z * NKV] + wp[3] * vbase[(size_t)i0.w * NKV] +
                wp[4] * vbase[(size_t)i1.x * NKV] + wp[5] * vbase[(size_t)i1.y * NKV] +
                wp[6] * vbase[(size_t)i1.z * NKV] + wp[7] * vbase[(size_t)i1.w * NKV];

    out[(size_t)gr * NKV + h * HD + lane] = acc;
}

extern "C" void kernel_launch(void* const* d_in, const int* in_sizes, int n_in,
                              void* d_out, int out_size, void* d_ws, size_t ws_size,
                              hipStream_t stream)
{
    const float* hs = (const float*)d_in[0];  // [4,2048,1024]
    const float* Wk = (const float*)d_in[1];  // [1024,1024]
    const float* bk = (const float*)d_in[2];  // [1024]
    const float* Wv = (const float*)d_in[3];  // [1024,1024]
    const float* bv = (const float*)d_in[4];  // [1024]
    const float* RH = (const float*)d_in[5];  // [16,64]
    const float* bw = (const float*)d_in[6];  // [16,8]
    float* out = (float*)d_out;

    char* ws = (char*)d_ws;
    float* V1             = (float*)ws;                                         // 32 MiB
    unsigned char* validB = (unsigned char*)(ws + (size_t)M_TOT * NKV * 4);     // 128 KiB
    short* idxb           = (short*)(ws + (size_t)M_TOT * NKV * 4 + (size_t)M_TOT * NH); // 2 MiB, 16B-aligned

    dim3 g1(M_TOT / BM, NKV / BN);  // (64, 8)
    fused_gemm<0><<<g1, 256, 0, stream>>>(hs, Wv, bv, nullptr, V1, nullptr);
    fused_gemm<1><<<g1, 256, 0, stream>>>(hs, Wk, bk, RH, nullptr, validB);
    scan_kernel<<<BS * NH, 256, 0, stream>>>(validB, idxb);
    gather_kernel<<<(M_TOT * NH) / 4, 256, 0, stream>>>(V1, idxb, bw, out);
}

// Round 4
// 242.863 us; speedup vs baseline: 3.7764x; 2.2644x over previous
//
#include <hip/hip_runtime.h>
#include <hip/hip_bf16.h>
#include <stdint.h>

// Problem constants
#define BS   4
#define LSEQ 2048
#define HID  1024
#define NH   16
#define HD   64
#define M_TOT (BS * LSEQ)   // 8192
#define NKV   (NH * HD)     // 1024

typedef __attribute__((ext_vector_type(8))) short short8x;   // 8 bf16 (4 VGPR)
typedef __attribute__((ext_vector_type(4))) float f32x4;     // MFMA accum

__device__ __forceinline__ float relu_f(float x) { return x > 0.0f ? x : 0.0f; }

__device__ __forceinline__ ushort bf16_rne(float f) {
    uint32_t x = __float_as_uint(f);
    return (ushort)((x + 0x7FFFu + ((x >> 16) & 1u)) >> 16);
}
__device__ __forceinline__ float bf16_to_f(ushort h) {
    return __uint_as_float((uint32_t)h << 16);
}

__device__ __forceinline__ void gload_lds16(const void* g, void* l) {
    typedef __attribute__((address_space(1))) const uint32_t GU;
    typedef __attribute__((address_space(3))) uint32_t LU;
    __builtin_amdgcn_global_load_lds((GU*)g, (LU*)l, 16, 0, 0);
}

// ---------------- conversion kernels ----------------

// fp32 A [M,1024] -> Ahi,Alo bf16 bits [M,1024]
__global__ __launch_bounds__(256) void split_A(const float* __restrict__ A,
                                               ushort* __restrict__ hi,
                                               ushort* __restrict__ lo)
{
    int i = blockIdx.x * 256 + threadIdx.x;       // float4 index
    float4 v = ((const float4*)A)[i];
    ushort4 h, l;
    h.x = bf16_rne(v.x); l.x = bf16_rne(v.x - bf16_to_f(h.x));
    h.y = bf16_rne(v.y); l.y = bf16_rne(v.y - bf16_to_f(h.y));
    h.z = bf16_rne(v.z); l.z = bf16_rne(v.z - bf16_to_f(h.z));
    h.w = bf16_rne(v.w); l.w = bf16_rne(v.w - bf16_to_f(h.w));
    ((ushort4*)hi)[i] = h;
    ((ushort4*)lo)[i] = l;
}

// fp32 W [1024(k),1024(n)] -> hiT,loT bf16 bits [1024(n),1024(k)] (transposed)
__global__ __launch_bounds__(256) void split_WT(const float* __restrict__ W,
                                                ushort* __restrict__ hiT,
                                                ushort* __restrict__ loT)
{
    __shared__ float t[64][65];
    const int k0 = blockIdx.x * 64, n0 = blockIdx.y * 64;
    const int tid = threadIdx.x;
#pragma unroll
    for (int it = 0; it < 4; ++it) {
        int r = it * 16 + (tid >> 4);
        int c = (tid & 15) * 4;
        float4 v = *(const float4*)&W[(size_t)(k0 + r) * NKV + n0 + c];
        t[r][c] = v.x; t[r][c + 1] = v.y; t[r][c + 2] = v.z; t[r][c + 3] = v.w;
    }
    __syncthreads();
    int n  = tid >> 2;            // 0..63
    int kc = (tid & 3) * 16;      // 0,16,32,48
    ushort hb[16], lb[16];
#pragma unroll
    for (int j = 0; j < 16; ++j) {
        float f = t[kc + j][n];
        ushort h = bf16_rne(f);
        hb[j] = h;
        lb[j] = bf16_rne(f - bf16_to_f(h));
    }
    size_t o = (size_t)(n0 + n) * 1024 + k0 + kc;
    *(uint4*)&hiT[o]     = *(uint4*)&hb[0];
    *(uint4*)&hiT[o + 8] = *(uint4*)&hb[8];
    *(uint4*)&loT[o]     = *(uint4*)&lb[0];
    *(uint4*)&loT[o + 8] = *(uint4*)&lb[8];
}

// ---------------- fused split-bf16 MFMA GEMM ----------------
// grid (64, 16): y 0..7 -> V path (Wv), y 8..15 -> K path (Wk, dot+threshold)
// C = Ahi@Whi + Alo@Whi + Ahi@Wlo ; 128x128 tile, BK=64, 2x2 waves x 4x4 frags.
__global__ __launch_bounds__(256, 2) void mfma_gemm(
    const ushort* __restrict__ Ahi, const ushort* __restrict__ Alo,
    const ushort* __restrict__ WvhiT, const ushort* __restrict__ WvloT,
    const ushort* __restrict__ WkhiT, const ushort* __restrict__ WkloT,
    const float* __restrict__ bv, const float* __restrict__ bk,
    const float* __restrict__ RH,
    float* __restrict__ V1, unsigned char* __restrict__ validB)
{
    __shared__ ushort As[128 * 64];   // 16 KB, XOR-swizzled 16B chunks
    __shared__ ushort Bsh[128 * 64];  // 16 KB

    const int tid  = threadIdx.x;
    const int lane = tid & 63;
    const int wv   = tid >> 6;        // wave 0..3
    const int wm   = wv >> 1;         // wave row 0/1
    const int wn   = wv & 1;          // wave col 0/1
    const int bm   = blockIdx.x;
    const bool kpath = (blockIdx.y >= 8);
    const int bn   = blockIdx.y & 7;

    const ushort* WT_hi = kpath ? WkhiT : WvhiT;
    const ushort* WT_lo = kpath ? WkloT : WvloT;
    const float*  bias  = kpath ? bk : bv;

    f32x4 acc[4][4];
    const f32x4 z = {0.f, 0.f, 0.f, 0.f};
#pragma unroll
    for (int i = 0; i < 4; ++i)
#pragma unroll
        for (int j = 0; j < 4; ++j) acc[i][j] = z;

    // staging geometry: tile = 128 rows x 64 bf16 (128B rows = 8 x 16B chunks)
    // flat chunk f = it*256 + tid ; r = f>>3, c = f&7 ; LDS linear, global src
    // pre-swizzled: chunk fetched = c ^ (r&7).
    for (int ks = 0; ks < 48; ++ks) {
        const int seg = ks >> 4;
        const int k0  = (ks & 15) << 6;
        const ushort* Aseg = (seg == 1) ? Alo : Ahi;
        const ushort* Wseg = (seg == 2) ? WT_lo : WT_hi;

#pragma unroll
        for (int it = 0; it < 4; ++it) {
            int f = it * 256 + tid;
            int r = f >> 3, c = f & 7;
            const ushort* asrc = Aseg + (size_t)(bm * 128 + r) * 1024 + k0 + ((c ^ (r & 7)) << 3);
            gload_lds16(asrc, &As[(size_t)(it * 256 + wv * 64) * 8]);
        }
#pragma unroll
        for (int it = 0; it < 4; ++it) {
            int f = it * 256 + tid;
            int r = f >> 3, c = f & 7;
            const ushort* bsrc = Wseg + (size_t)(bn * 128 + r) * 1024 + k0 + ((c ^ (r & 7)) << 3);
            gload_lds16(bsrc, &Bsh[(size_t)(it * 256 + wv * 64) * 8]);
        }
        __syncthreads();

        short8x a[4][2], b[4][2];
#pragma unroll
        for (int mi = 0; mi < 4; ++mi)
#pragma unroll
            for (int k2 = 0; k2 < 2; ++k2) {
                int row = wm * 64 + mi * 16 + (lane & 15);
                int ch  = k2 * 4 + (lane >> 4);
                a[mi][k2] = *(const short8x*)((const char*)As + row * 128 + ((ch ^ (row & 7)) << 4));
            }
#pragma unroll
        for (int ni = 0; ni < 4; ++ni)
#pragma unroll
            for (int k2 = 0; k2 < 2; ++k2) {
                int row = wn * 64 + ni * 16 + (lane & 15);
                int ch  = k2 * 4 + (lane >> 4);
                b[ni][k2] = *(const short8x*)((const char*)Bsh + row * 128 + ((ch ^ (row & 7)) << 4));
            }

#pragma unroll
        for (int k2 = 0; k2 < 2; ++k2)
#pragma unroll
            for (int mi = 0; mi < 4; ++mi)
#pragma unroll
                for (int ni = 0; ni < 4; ++ni)
                    acc[mi][ni] = __builtin_amdgcn_mfma_f32_16x16x32_bf16(
                        a[mi][k2], b[ni][k2], acc[mi][ni], 0, 0, 0);
        __syncthreads();
    }

    // epilogue ; C/D layout: col = lane&15, row = (lane>>4)*4 + reg
    if (!kpath) {
#pragma unroll
        for (int mi = 0; mi < 4; ++mi)
#pragma unroll
            for (int ni = 0; ni < 4; ++ni) {
                int row0 = bm * 128 + wm * 64 + mi * 16 + (lane >> 4) * 4;
                int col  = bn * 128 + wn * 64 + ni * 16 + (lane & 15);
                float bc = bias[col];
#pragma unroll
                for (int r = 0; r < 4; ++r)
                    V1[(size_t)(row0 + r) * NKV + col] = relu_f(acc[mi][ni][r] + bc);
            }
    } else {
        const int head = bn * 2 + wn;
        float rhw[4], bcs[4];
#pragma unroll
        for (int ni = 0; ni < 4; ++ni) {
            int ch = ni * 16 + (lane & 15);                 // col within head
            rhw[ni] = RH[head * HD + ch];
            bcs[ni] = bias[bn * 128 + wn * 64 + ch];
        }
#pragma unroll
        for (int mi = 0; mi < 4; ++mi) {
            float s[4];
#pragma unroll
            for (int r = 0; r < 4; ++r) {
                float v = 0.f;
#pragma unroll
                for (int ni = 0; ni < 4; ++ni)
                    v += relu_f(acc[mi][ni][r] + bcs[ni]) * rhw[ni];
                s[r] = v;
            }
#pragma unroll
            for (int m = 1; m < 16; m <<= 1)
#pragma unroll
                for (int r = 0; r < 4; ++r)
                    s[r] += __shfl_xor(s[r], m);
            if ((lane & 15) == 0) {
#pragma unroll
                for (int r = 0; r < 4; ++r) {
                    int grow = bm * 128 + wm * 64 + mi * 16 + (lane >> 4) * 4 + r;
                    int bb = grow >> 11, ll = grow & 2047;
                    validB[((size_t)bb * NH + head) * LSEQ + ll] = (s[r] > 0.5f) ? 1 : 0;
                }
            }
        }
    }
}

// ---------------- parallel register-map extraction ----------------
__global__ __launch_bounds__(256) void scan_kernel(
    const unsigned char* __restrict__ validB,
    short* __restrict__ idxb)   // [M_TOT][NH][8]: slots 0..3 fwd, 4..7 bwd
{
    const int bh = blockIdx.x;      // 0..63
    const int b  = bh >> 4;
    const int h  = bh & 15;
    const unsigned char* v = validB + ((size_t)b * NH + h) * LSEQ;

    __shared__ uint64_t words[LSEQ / 64];

    const int tid  = threadIdx.x;
    const int lane = tid & 63;
    const int wv   = tid >> 6;

#pragma unroll
    for (int it = 0; it < LSEQ / 256; ++it) {
        int p = it * 256 + wv * 64 + lane;
        uint64_t m = __ballot(v[p] != 0);
        if (lane == 0) {
            if ((p >> 6) == 0) m &= ~1ull;
            words[p >> 6] = m;
        }
    }
    __syncthreads();

#pragma unroll
    for (int it = 0; it < LSEQ / 256; ++it) {
        int l = it * 256 + tid;
        ushort f[4] = {0, 0, 0, 0};
        ushort g[4] = {0, 0, 0, 0};
        if (l > 0) {
            {   // forward: last 4 set bits <= l
                int wi = l >> 6, bi = l & 63;
                uint64_t m = words[wi] & ((bi == 63) ? ~0ull : ((2ull << bi) - 1));
                int cnt = 0;
                while (cnt < 4) {
                    if (m == 0) { if (wi == 0) break; m = words[--wi]; continue; }
                    int p = 63 - __clzll(m);
                    f[cnt++] = (ushort)(wi * 64 + p);
                    m &= ~(1ull << p);
                }
            }
            {   // backward: first 4 set bits >= l, value min(p+1, L-1)
                int wi = l >> 6, bi = l & 63;
                uint64_t m = words[wi] & (~0ull << bi);
                int cnt = 0;
                while (cnt < 4) {
                    if (m == 0) { if (wi == (LSEQ / 64) - 1) break; m = words[++wi]; continue; }
                    int p = __ffsll((long long)m) - 1;
                    int pos = wi * 64 + p;
                    g[cnt++] = (ushort)((pos >= LSEQ - 1) ? (LSEQ - 1) : (pos + 1));
                    m &= m - 1;
                }
            }
        }
        uint4 pk;
        pk.x = (uint32_t)f[0] | ((uint32_t)f[1] << 16);
        pk.y = (uint32_t)f[2] | ((uint32_t)f[3] << 16);
        pk.z = (uint32_t)g[0] | ((uint32_t)g[1] << 16);
        pk.w = (uint32_t)g[2] | ((uint32_t)g[3] << 16);
        *(uint4*)(idxb + (((size_t)(b * LSEQ + l)) * NH + h) * 8) = pk;
    }
}

// ---------------- weighted 8-way gather ----------------
__global__ __launch_bounds__(256) void gather_kernel(
    const float* __restrict__ V1,
    const short* __restrict__ idxb,
    const float* __restrict__ bw,
    float* __restrict__ out)
{
    int wid  = (blockIdx.x * 256 + threadIdx.x) >> 6;
    int lane = threadIdx.x & 63;
    int gr   = wid >> 4;
    int h    = wid & 15;
    int b    = gr >> 11;

    const ushort4* ip = (const ushort4*)(idxb + ((size_t)gr * NH + h) * 8);
    ushort4 i0 = ip[0];
    ushort4 i1 = ip[1];

    const float* wp    = bw + h * 8;
    const float* vbase = V1 + (size_t)b * LSEQ * NKV + h * HD + lane;

    float acc = wp[0] * vbase[(size_t)i0.x * NKV] + wp[1] * vbase[(size_t)i0.y * NKV] +
                wp[2] * vbase[(size_t)i0.z * NKV] + wp[3] * vbase[(size_t)i0.w * NKV] +
                wp[4] * vbase[(size_t)i1.x * NKV] + wp[5] * vbase[(size_t)i1.y * NKV] +
                wp[6] * vbase[(size_t)i1.z * NKV] + wp[7] * vbase[(size_t)i1.w * NKV];

    out[(size_t)gr * NKV + h * HD + lane] = acc;
}

extern "C" void kernel_launch(void* const* d_in, const int* in_sizes, int n_in,
                              void* d_out, int out_size, void* d_ws, size_t ws_size,
                              hipStream_t stream)
{
    const float* hs = (const float*)d_in[0];  // [4,2048,1024]
    const float* Wk = (const float*)d_in[1];  // [1024,1024]
    const float* bk = (const float*)d_in[2];  // [1024]
    const float* Wv = (const float*)d_in[3];  // [1024,1024]
    const float* bv = (const float*)d_in[4];  // [1024]
    const float* RH = (const float*)d_in[5];  // [16,64]
    const float* bw = (const float*)d_in[6];  // [16,8]
    float* out = (float*)d_out;

    char* ws = (char*)d_ws;
    size_t o = 0;
    float* V1      = (float*)(ws + o);  o += (size_t)M_TOT * NKV * 4;      // 32 MiB
    ushort* Ahi    = (ushort*)(ws + o); o += (size_t)M_TOT * HID * 2;      // 16 MiB
    ushort* Alo    = (ushort*)(ws + o); o += (size_t)M_TOT * HID * 2;      // 16 MiB
    ushort* WvhiT  = (ushort*)(ws + o); o += (size_t)HID * NKV * 2;        // 2 MiB
    ushort* WvloT  = (ushort*)(ws + o); o += (size_t)HID * NKV * 2;
    ushort* WkhiT  = (ushort*)(ws + o); o += (size_t)HID * NKV * 2;
    ushort* WkloT  = (ushort*)(ws + o); o += (size_t)HID * NKV * 2;
    unsigned char* validB = (unsigned char*)(ws + o); o += (size_t)BS * NH * LSEQ; // 128 KiB
    short* idxb    = (short*)(ws + o);  o += (size_t)M_TOT * NH * 8 * 2;   // 2 MiB

    split_A<<<(M_TOT * HID / 4) / 256, 256, 0, stream>>>(hs, Ahi, Alo);
    split_WT<<<dim3(16, 16), 256, 0, stream>>>(Wv, WvhiT, WvloT);
    split_WT<<<dim3(16, 16), 256, 0, stream>>>(Wk, WkhiT, WkloT);
    mfma_gemm<<<dim3(M_TOT / 128, 16), 256, 0, stream>>>(
        Ahi, Alo, WvhiT, WvloT, WkhiT, WkloT, bv, bk, RH, V1, validB);
    scan_kernel<<<BS * NH, 256, 0, stream>>>(validB, idxb);
    gather_kernel<<<(M_TOT * NH) / 4, 256, 0, stream>>>(V1, idxb, bw, out);
}

// Round 7
// 228.174 us; speedup vs baseline: 4.0195x; 1.0644x over previous
//
#include <hip/hip_runtime.h>
#include <hip/hip_bf16.h>
#include <stdint.h>

// Problem constants
#define BS   4
#define LSEQ 2048
#define HID  1024
#define NH   16
#define HD   64
#define M_TOT (BS * LSEQ)   // 8192
#define NKV   (NH * HD)     // 1024
#define NIT   24            // 48 K-tiles of 64 (K_eff = 3*1024), 2 per iteration

typedef __attribute__((ext_vector_type(8))) short short8x;   // 8 bf16
typedef __attribute__((ext_vector_type(4))) float f32x4;     // MFMA accum

__device__ __forceinline__ float relu_f(float x) { return x > 0.0f ? x : 0.0f; }

__device__ __forceinline__ ushort bf16_rne(float f) {
    uint32_t x = __float_as_uint(f);
    return (ushort)((x + 0x7FFFu + ((x >> 16) & 1u)) >> 16);
}
__device__ __forceinline__ float bf16_to_f(ushort h) {
    return __uint_as_float((uint32_t)h << 16);
}

__device__ __forceinline__ void gload_lds16(const void* g, void* l) {
    typedef __attribute__((address_space(1))) const uint32_t GU;
    typedef __attribute__((address_space(3))) uint32_t LU;
    __builtin_amdgcn_global_load_lds((GU*)g, (LU*)l, 16, 0, 0);
}

// ---------------- fused prep: A hi/lo split + both W hi/lo transposed splits ----------------
__global__ __launch_bounds__(256) void prep(
    const float* __restrict__ A,
    const float* __restrict__ Wv, const float* __restrict__ Wk,
    ushort* __restrict__ Ahi, ushort* __restrict__ Alo,
    ushort* __restrict__ WvhiT, ushort* __restrict__ WvloT,
    ushort* __restrict__ WkhiT, ushort* __restrict__ WkloT)
{
    __shared__ float t[64][65];
    const int bid = blockIdx.x;
    const int tid = threadIdx.x;
    if (bid < 8192) {
        // A split: one float4 per thread
        int i = bid * 256 + tid;
        float4 v = ((const float4*)A)[i];
        ushort4 h, l;
        h.x = bf16_rne(v.x); l.x = bf16_rne(v.x - bf16_to_f(h.x));
        h.y = bf16_rne(v.y); l.y = bf16_rne(v.y - bf16_to_f(h.y));
        h.z = bf16_rne(v.z); l.z = bf16_rne(v.z - bf16_to_f(h.z));
        h.w = bf16_rne(v.w); l.w = bf16_rne(v.w - bf16_to_f(h.w));
        ((ushort4*)Ahi)[i] = h;
        ((ushort4*)Alo)[i] = l;
    } else {
        // W transpose + split: 512 blocks, 64x64 tiles
        int idx = bid - 8192;                 // 0..511
        const float* W  = (idx < 256) ? Wv : Wk;
        ushort* hiT     = (idx < 256) ? WvhiT : WkhiT;
        ushort* loT     = (idx < 256) ? WvloT : WkloT;
        int tt = idx & 255;
        int k0 = (tt >> 4) * 64, n0 = (tt & 15) * 64;
#pragma unroll
        for (int it = 0; it < 4; ++it) {
            int r = it * 16 + (tid >> 4);
            int c = (tid & 15) * 4;
            float4 v = *(const float4*)&W[(size_t)(k0 + r) * NKV + n0 + c];
            t[r][c] = v.x; t[r][c + 1] = v.y; t[r][c + 2] = v.z; t[r][c + 3] = v.w;
        }
        __syncthreads();
        int n  = tid >> 2;            // 0..63
        int kc = (tid & 3) * 16;      // 0,16,32,48
        ushort hb[16], lb[16];
#pragma unroll
        for (int j = 0; j < 16; ++j) {
            float f = t[kc + j][n];
            ushort h = bf16_rne(f);
            hb[j] = h;
            lb[j] = bf16_rne(f - bf16_to_f(h));
        }
        size_t o = (size_t)(n0 + n) * 1024 + k0 + kc;
        *(uint4*)&hiT[o]     = *(uint4*)&hb[0];
        *(uint4*)&hiT[o + 8] = *(uint4*)&hb[8];
        *(uint4*)&loT[o]     = *(uint4*)&lb[0];
        *(uint4*)&loT[o + 8] = *(uint4*)&lb[8];
    }
}

// ---------------- 256x256 8-phase split-bf16 MFMA GEMM ----------------
// grid (32, 8): y 0..3 -> V path (Wv), y 4..7 -> K path (Wk, dot+threshold)
// C = Ahi@Whi + Alo@Whi + Ahi@Wlo over 48 K-tiles of 64.
// 8 waves (2M x 4N), per-wave output 128x64. Even K-tiles buf0, odd buf1.
//
// Staging hazard map (the round-6 bug fix):
//   LA[buf] rows are read at P1 (READ_A(.,0): rows wm*128+0..63) AND
//   P3 (READ_A(.,1): rows wm*128+64..127) -> LA may only be staged at P4.
//   LB[buf] rows are read at P1 (READ_B(.,0)) and P2 (READ_B(.,1)) ->
//   LB may be staged at P3. 8 loads/thread per K-tile (4 at P3, 4 at P4),
//   so vmcnt(8) at P4/P8 still == "previous K-tile's loads landed".
__global__ __launch_bounds__(512, 2) void mfma_gemm(
    const ushort* __restrict__ Ahi, const ushort* __restrict__ Alo,
    const ushort* __restrict__ WvhiT, const ushort* __restrict__ WvloT,
    const ushort* __restrict__ WkhiT, const ushort* __restrict__ WkloT,
    const float* __restrict__ bv, const float* __restrict__ bk,
    const float* __restrict__ RH,
    float* __restrict__ V1, unsigned char* __restrict__ validB)
{
    __shared__ ushort LA[2][256 * 64];   // 2 x 32 KiB
    __shared__ ushort LB[2][256 * 64];   // 2 x 32 KiB

    const int tid  = threadIdx.x;        // 0..511
    const int lane = tid & 63;
    const int wv   = tid >> 6;           // 0..7
    const int wm   = wv >> 2;            // 0/1
    const int wn   = wv & 3;             // 0..3
    const int bm   = blockIdx.x;
    const bool kpath = (blockIdx.y >= 4);
    const int bnl  = kpath ? (blockIdx.y - 4) : blockIdx.y;

    const ushort* Whi  = kpath ? WkhiT : WvhiT;
    const ushort* Wlo  = kpath ? WkloT : WvloT;
    const float*  bias = kpath ? bk : bv;

    f32x4 acc[8][4];
    const f32x4 zz = {0.f, 0.f, 0.f, 0.f};
#pragma unroll
    for (int i = 0; i < 8; ++i)
#pragma unroll
        for (int j = 0; j < 4; ++j) acc[i][j] = zz;

    // Lane-constant swizzled read-chunk offsets (shorts). row&7 == lane&7 since
    // frag rows differ from (lane&15) by multiples of 16.
    const int rc0 = ((0 + (lane >> 4)) ^ (lane & 7)) * 8;   // k2=0
    const int rc1 = ((4 + (lane >> 4)) ^ (lane & 7)) * 8;   // k2=1

    // Tile source pointers (half = 0/1 -> rows 0..127 / 128..255 of the 256-row panel)
    auto Asrc = [&](int kt, int half) -> const ushort* {
        const ushort* base = ((kt >> 4) == 1) ? Alo : Ahi;
        return base + (size_t)(bm * 256 + half * 128) * 1024 + ((kt & 15) << 6);
    };
    auto Bsrc = [&](int kt, int half) -> const ushort* {
        const ushort* base = ((kt >> 4) == 2) ? Wlo : Whi;
        return base + (size_t)(bnl * 256 + half * 128) * 1024 + ((kt & 15) << 6);
    };

// stage one half-tile (128 rows x 64 bf16 = 1024 x 16B chunks) via global_load_lds.
// LDS linear; global source pre-swizzled chunk c^(r&7). dst: shorts pointer.
#define STAGE_HALF(dst, src) do {                                              \
    _Pragma("unroll")                                                          \
    for (int it_ = 0; it_ < 2; ++it_) {                                        \
        int f_ = it_ * 512 + tid;                                              \
        int r_ = f_ >> 3, c_ = f_ & 7;                                         \
        gload_lds16((src) + (size_t)r_ * 1024 + ((c_ ^ (r_ & 7)) << 3),        \
                    (dst) + (size_t)(it_ * 512 + wv * 64) * 8);                \
    }                                                                          \
} while (0)

#define READ_A(buf, half) do {                                                 \
    _Pragma("unroll")                                                          \
    for (int mi_ = 0; mi_ < 4; ++mi_) {                                        \
        int row_ = wm * 128 + (half) * 64 + mi_ * 16 + (lane & 15);            \
        const ushort* b_ = &LA[buf][row_ * 64];                                \
        a_f[mi_][0] = *(const short8x*)(b_ + rc0);                             \
        a_f[mi_][1] = *(const short8x*)(b_ + rc1);                             \
    }                                                                          \
} while (0)

#define READ_B(buf, half) do {                                                 \
    _Pragma("unroll")                                                          \
    for (int nj_ = 0; nj_ < 2; ++nj_) {                                        \
        int ni_ = (half) * 2 + nj_;                                            \
        int row_ = wn * 64 + ni_ * 16 + (lane & 15);                           \
        const ushort* b_ = &LB[buf][row_ * 64];                                \
        b_f[ni_][0] = *(const short8x*)(b_ + rc0);                             \
        b_f[ni_][1] = *(const short8x*)(b_ + rc1);                             \
    }                                                                          \
} while (0)

#define MFMA_QUAD(mh, nh) do {                                                 \
    _Pragma("unroll")                                                          \
    for (int k2_ = 0; k2_ < 2; ++k2_)                                          \
        _Pragma("unroll")                                                      \
        for (int mi_ = 0; mi_ < 4; ++mi_)                                      \
            _Pragma("unroll")                                                  \
            for (int nj_ = 0; nj_ < 2; ++nj_) {                                \
                int ni_ = (nh) * 2 + nj_;                                      \
                acc[(mh) * 4 + mi_][ni_] =                                     \
                    __builtin_amdgcn_mfma_f32_16x16x32_bf16(                   \
                        a_f[mi_][k2_], b_f[ni_][k2_], acc[(mh) * 4 + mi_][ni_],\
                        0, 0, 0);                                              \
            }                                                                  \
} while (0)

#define PHASE_SYNC()                                                           \
    __builtin_amdgcn_s_barrier();                                              \
    asm volatile("s_waitcnt lgkmcnt(0)" ::: "memory");                         \
    __builtin_amdgcn_sched_barrier(0);                                         \
    __builtin_amdgcn_s_setprio(1)

#define PHASE_END()                                                            \
    __builtin_amdgcn_s_setprio(0);                                             \
    __builtin_amdgcn_s_barrier()

    short8x a_f[4][2], b_f[4][2];

    // Prologue: stage K-tiles 0 (buf0) and 1 (buf1) = 16 loads/thread.
    STAGE_HALF(&LA[0][0],    Asrc(0, 0));
    STAGE_HALF(&LA[0][8192], Asrc(0, 1));
    STAGE_HALF(&LB[0][0],    Bsrc(0, 0));
    STAGE_HALF(&LB[0][8192], Bsrc(0, 1));
    STAGE_HALF(&LA[1][0],    Asrc(1, 0));
    STAGE_HALF(&LA[1][8192], Asrc(1, 1));
    STAGE_HALF(&LB[1][0],    Bsrc(1, 0));
    STAGE_HALF(&LB[1][8192], Bsrc(1, 1));
    asm volatile("s_waitcnt vmcnt(8)" ::: "memory");   // K-tile 0 landed
    __builtin_amdgcn_s_barrier();

#pragma unroll 1
    for (int i = 0; i < NIT; ++i) {
        const int kt0 = 2 * i;
        const int kt1 = 2 * i + 1;
        const bool st = (i < NIT - 1);

        // ---- P1: quad(0,0) of kt0 ----
        READ_A(0, 0); READ_B(0, 0);
        PHASE_SYNC();
        MFMA_QUAD(0, 0);
        PHASE_END();

        // ---- P2: quad(0,1) ----
        READ_B(0, 1);
        PHASE_SYNC();
        MFMA_QUAD(0, 1);
        PHASE_END();

        // ---- P3: quad(1,1); LB[0] fully read after P2 -> stage B(kt0+2) ----
        READ_A(0, 1);
        if (st) {
            STAGE_HALF(&LB[0][0],    Bsrc(kt0 + 2, 0));
            STAGE_HALF(&LB[0][8192], Bsrc(kt0 + 2, 1));
        }
        PHASE_SYNC();
        MFMA_QUAD(1, 1);
        PHASE_END();

        // ---- P4: quad(1,0); LA[0] fully read after P3 -> stage A(kt0+2) ----
        if (st) {
            STAGE_HALF(&LA[0][0],    Asrc(kt0 + 2, 0));
            STAGE_HALF(&LA[0][8192], Asrc(kt0 + 2, 1));
        }
        PHASE_SYNC();
        MFMA_QUAD(1, 0);
        __builtin_amdgcn_s_setprio(0);
        if (st) asm volatile("s_waitcnt vmcnt(8)" ::: "memory");  // kt1 landed
        else    asm volatile("s_waitcnt vmcnt(0)" ::: "memory");
        __builtin_amdgcn_s_barrier();

        // ---- P5: quad(0,0) of kt1 (buf1) ----
        READ_A(1, 0); READ_B(1, 0);
        PHASE_SYNC();
        MFMA_QUAD(0, 0);
        PHASE_END();

        // ---- P6: quad(0,1) ----
        READ_B(1, 1);
        PHASE_SYNC();
        MFMA_QUAD(0, 1);
        PHASE_END();

        // ---- P7: quad(1,1); stage B(kt1+2) ----
        READ_A(1, 1);
        if (st) {
            STAGE_HALF(&LB[1][0],    Bsrc(kt1 + 2, 0));
            STAGE_HALF(&LB[1][8192], Bsrc(kt1 + 2, 1));
        }
        PHASE_SYNC();
        MFMA_QUAD(1, 1);
        PHASE_END();

        // ---- P8: quad(1,0); stage A(kt1+2) ----
        if (st) {
            STAGE_HALF(&LA[1][0],    Asrc(kt1 + 2, 1 - 1));
            STAGE_HALF(&LA[1][8192], Asrc(kt1 + 2, 1));
        }
        PHASE_SYNC();
        MFMA_QUAD(1, 0);
        __builtin_amdgcn_s_setprio(0);
        if (st) asm volatile("s_waitcnt vmcnt(8)" ::: "memory");  // next kt0 landed
        __builtin_amdgcn_s_barrier();
    }

    // ---- epilogue ----  C/D layout: col = lane&15, row = (lane>>4)*4 + reg
    if (!kpath) {
#pragma unroll
        for (int mi = 0; mi < 8; ++mi)
#pragma unroll
            for (int ni = 0; ni < 4; ++ni) {
                int row0 = bm * 256 + wm * 128 + mi * 16 + (lane >> 4) * 4;
                int col  = bnl * 256 + wn * 64 + ni * 16 + (lane & 15);
                float bc = bias[col];
#pragma unroll
                for (int r = 0; r < 4; ++r)
                    V1[(size_t)(row0 + r) * NKV + col] = relu_f(acc[mi][ni][r] + bc);
            }
    } else {
        const int head = bnl * 4 + wn;     // wave column == one head (64 cols)
        float rhw[4], bcs[4];
#pragma unroll
        for (int ni = 0; ni < 4; ++ni) {
            int ch = ni * 16 + (lane & 15);
            rhw[ni] = RH[head * HD + ch];
            bcs[ni] = bias[head * HD + ch];
        }
#pragma unroll
        for (int mi = 0; mi < 8; ++mi) {
            float s[4];
#pragma unroll
            for (int r = 0; r < 4; ++r) {
                float v = 0.f;
#pragma unroll
                for (int ni = 0; ni < 4; ++ni)
                    v += relu_f(acc[mi][ni][r] + bcs[ni]) * rhw[ni];
                s[r] = v;
            }
#pragma unroll
            for (int m = 1; m < 16; m <<= 1)
#pragma unroll
                for (int r = 0; r < 4; ++r)
                    s[r] += __shfl_xor(s[r], m);
            if ((lane & 15) == 0) {
#pragma unroll
                for (int r = 0; r < 4; ++r) {
                    int grow = bm * 256 + wm * 128 + mi * 16 + (lane >> 4) * 4 + r;
                    int bb = grow >> 11, ll = grow & 2047;
                    validB[((size_t)bb * NH + head) * LSEQ + ll] = (s[r] > 0.5f) ? 1 : 0;
                }
            }
        }
    }
#undef STAGE_HALF
#undef READ_A
#undef READ_B
#undef MFMA_QUAD
#undef PHASE_SYNC
#undef PHASE_END
}

// ---------------- parallel register-map extraction ----------------
__global__ __launch_bounds__(256) void scan_kernel(
    const unsigned char* __restrict__ validB,
    short* __restrict__ idxb)   // [M_TOT][NH][8]: slots 0..3 fwd, 4..7 bwd
{
    const int bh = blockIdx.x;      // 0..63
    const int b  = bh >> 4;
    const int h  = bh & 15;
    const unsigned char* v = validB + ((size_t)b * NH + h) * LSEQ;

    __shared__ uint64_t words[LSEQ / 64];

    const int tid  = threadIdx.x;
    const int lane = tid & 63;
    const int wv   = tid >> 6;

#pragma unroll
    for (int it = 0; it < LSEQ / 256; ++it) {
        int p = it * 256 + wv * 64 + lane;
        uint64_t m = __ballot(v[p] != 0);
        if (lane == 0) {
            if ((p >> 6) == 0) m &= ~1ull;
            words[p >> 6] = m;
        }
    }
    __syncthreads();

#pragma unroll
    for (int it = 0; it < LSEQ / 256; ++it) {
        int l = it * 256 + tid;
        ushort f[4] = {0, 0, 0, 0};
        ushort g[4] = {0, 0, 0, 0};
        if (l > 0) {
            {   // forward: last 4 set bits <= l
                int wi = l >> 6, bi = l & 63;
                uint64_t m = words[wi] & ((bi == 63) ? ~0ull : ((2ull << bi) - 1));
                int cnt = 0;
                while (cnt < 4) {
                    if (m == 0) { if (wi == 0) break; m = words[--wi]; continue; }
                    int p = 63 - __clzll(m);
                    f[cnt++] = (ushort)(wi * 64 + p);
                    m &= ~(1ull << p);
                }
            }
            {   // backward: first 4 set bits >= l, value min(p+1, L-1)
                int wi = l >> 6, bi = l & 63;
                uint64_t m = words[wi] & (~0ull << bi);
                int cnt = 0;
                while (cnt < 4) {
                    if (m == 0) { if (wi == (LSEQ / 64) - 1) break; m = words[++wi]; continue; }
                    int p = __ffsll((long long)m) - 1;
                    int pos = wi * 64 + p;
                    g[cnt++] = (ushort)((pos >= LSEQ - 1) ? (LSEQ - 1) : (pos + 1));
                    m &= m - 1;
                }
            }
        }
        uint4 pk;
        pk.x = (uint32_t)f[0] | ((uint32_t)f[1] << 16);
        pk.y = (uint32_t)f[2] | ((uint32_t)f[3] << 16);
        pk.z = (uint32_t)g[0] | ((uint32_t)g[1] << 16);
        pk.w = (uint32_t)g[2] | ((uint32_t)g[3] << 16);
        *(uint4*)(idxb + (((size_t)(b * LSEQ + l)) * NH + h) * 8) = pk;
    }
}

// ---------------- weighted 8-way gather ----------------
__global__ __launch_bounds__(256) void gather_kernel(
    const float* __restrict__ V1,
    const short* __restrict__ idxb,
    const float* __restrict__ bw,
    float* __restrict__ out)
{
    int wid  = (blockIdx.x * 256 + threadIdx.x) >> 6;
    int lane = threadIdx.x & 63;
    int gr   = wid >> 4;
    int h    = wid & 15;
    int b    = gr >> 11;

    const ushort4* ip = (const ushort4*)(idxb + ((size_t)gr * NH + h) * 8);
    ushort4 i0 = ip[0];
    ushort4 i1 = ip[1];

    const float* wp    = bw + h * 8;
    const float* vbase = V1 + (size_t)b * LSEQ * NKV + h * HD + lane;

    float acc = wp[0] * vbase[(size_t)i0.x * NKV] + wp[1] * vbase[(size_t)i0.y * NKV] +
                wp[2] * vbase[(size_t)i0.z * NKV] + wp[3] * vbase[(size_t)i0.w * NKV] +
                wp[4] * vbase[(size_t)i1.x * NKV] + wp[5] * vbase[(size_t)i1.y * NKV] +
                wp[6] * vbase[(size_t)i1.z * NKV] + wp[7] * vbase[(size_t)i1.w * NKV];

    out[(size_t)gr * NKV + h * HD + lane] = acc;
}

extern "C" void kernel_launch(void* const* d_in, const int* in_sizes, int n_in,
                              void* d_out, int out_size, void* d_ws, size_t ws_size,
                              hipStream_t stream)
{
    const float* hs = (const float*)d_in[0];  // [4,2048,1024]
    const float* Wk = (const float*)d_in[1];  // [1024,1024]
    const float* bk = (const float*)d_in[2];  // [1024]
    const float* Wv = (const float*)d_in[3];  // [1024,1024]
    const float* bv = (const float*)d_in[4];  // [1024]
    const float* RH = (const float*)d_in[5];  // [16,64]
    const float* bw = (const float*)d_in[6];  // [16,8]
    float* out = (float*)d_out;

    char* ws = (char*)d_ws;
    size_t o = 0;
    float* V1      = (float*)(ws + o);  o += (size_t)M_TOT * NKV * 4;      // 32 MiB
    ushort* Ahi    = (ushort*)(ws + o); o += (size_t)M_TOT * HID * 2;      // 16 MiB
    ushort* Alo    = (ushort*)(ws + o); o += (size_t)M_TOT * HID * 2;      // 16 MiB
    ushort* WvhiT  = (ushort*)(ws + o); o += (size_t)HID * NKV * 2;        // 2 MiB
    ushort* WvloT  = (ushort*)(ws + o); o += (size_t)HID * NKV * 2;
    ushort* WkhiT  = (ushort*)(ws + o); o += (size_t)HID * NKV * 2;
    ushort* WkloT  = (ushort*)(ws + o); o += (size_t)HID * NKV * 2;
    unsigned char* validB = (unsigned char*)(ws + o); o += (size_t)BS * NH * LSEQ; // 128 KiB
    short* idxb    = (short*)(ws + o);  o += (size_t)M_TOT * NH * 8 * 2;   // 2 MiB

    prep<<<8192 + 512, 256, 0, stream>>>(hs, Wv, Wk, Ahi, Alo,
                                         WvhiT, WvloT, WkhiT, WkloT);
    mfma_gemm<<<dim3(M_TOT / 256, 8), 512, 0, stream>>>(
        Ahi, Alo, WvhiT, WvloT, WkhiT, WkloT, bv, bk, RH, V1, validB);
    scan_kernel<<<BS * NH, 256, 0, stream>>>(validB, idxb);
    gather_kernel<<<(M_TOT * NH) / 4, 256, 0, stream>>>(V1, idxb, bw, out);
}